// Round 12
// baseline (253.912 us; speedup 1.0000x reference)
//
#include <hip/hip_runtime.h>
#include <hip/hip_bf16.h>

#define Mm 8
#define Nn 512
#define NEe 409
#define NIi 103
#define Bb 512
#define Dd 243
#define Tt 16
#define SPROW 640      // spike row bytes (i8): e[0:409) pad[409:512) i[512:615) pad[615:640)
#define WCROW 1152     // packed weight row bytes (i8): inter(512) | E-rec(512) | I-rec(128)
#define DEC_I 0.33333334f  // (float)(1.0 - 1.0/1.5)
#define NBLK 256
#define FLAGSTRIDE 16  // one flag per 64B cache line
#define SPINMAX 1000000L

typedef int v4i __attribute__((ext_vector_type(4)));
union LV { long l[2]; v4i v; };

__device__ __forceinline__ float quantf(float w) {
    // fake_quant forward == clip(round-half-even(w), -8, 7)  (step = 1.0)
    float q = rintf(w);
    return fminf(fmaxf(q, -8.0f), 7.0f);
}

// ---------------- pack quantized recurrent weights as i8, 4 k's per thread ----------
__global__ void k_pack(const float* __restrict__ Wint, const float* __restrict__ WEE,
                       const float* __restrict__ WEI, const float* __restrict__ WIE,
                       const float* __restrict__ WII, signed char* __restrict__ Wc) {
    int q = blockIdx.x * 256 + threadIdx.x;          // quad index
    if (q >= (Mm * Nn * WCROW) / 4) return;
    int k0 = (q * 4) % WCROW;
    int n  = ((q * 4) / WCROW) & (Nn - 1);
    int m  = (q * 4) / (WCROW * Nn);
    char out4[4];
#pragma unroll
    for (int j = 0; j < 4; ++j) {
        int k = k0 + j;
        float w = 0.0f;
        if (k < 512) {
            if (k < NEe) w = Wint[((((m + 7) & 7) * Nn) + n) * NEe + k];
        } else if (k < 1024) {
            int jj = k - 512;
            if (jj < NEe) w = (n < NEe) ? WEE[((m * NEe) + n) * NEe + jj]
                                        : WEI[((m * NIi) + (n - NEe)) * NEe + jj];
        } else {
            int jj = k - 1024;
            if (jj < NIi) w = (n < NEe) ? WIE[((m * NEe) + n) * NIi + jj]
                                        : WII[((m * NIi) + (n - NEe)) * NIi + jj];
        }
        out4[j] = (signed char)(int)quantf(w);
    }
    *(int*)&Wc[q * 4] = *(int*)out4;
}

// ---------------- ext_proj = x @ qW_in^T + b_in  (fp32, sequential over d; r8 exact) -
__global__ void k_ext(const float* __restrict__ x, const float* __restrict__ Win,
                      const float* __restrict__ bin, float* __restrict__ ext) {
    __shared__ float xs[64][68];
    __shared__ float wsm[64][68];
    const int bid = blockIdx.x;          // 512 blocks: m(8) x bt(8) x nt(8)
    const int m  = bid >> 6;
    const int bt = (bid >> 3) & 7;
    const int nt = bid & 7;
    const int b0 = bt * 64, n0 = nt * 64;
    const int t = threadIdx.x;
    const int tb4 = (t & 15) * 4;
    const int tn4 = (t >> 4) * 4;
    const int sr = t >> 2;
    const int sc = (t & 3) * 16;
    float c[4][4];
#pragma unroll
    for (int i = 0; i < 4; ++i)
#pragma unroll
        for (int j = 0; j < 4; ++j) c[i][j] = 0.0f;

    for (int d0 = 0; d0 < Dd; d0 += 64) {
#pragma unroll
        for (int j = 0; j < 16; ++j) {
            int d = d0 + sc + j;
            float xv = 0.0f, wv = 0.0f;
            if (d < Dd) {
                xv = x[(b0 + sr) * Dd + d];
                wv = quantf(Win[((m * Nn) + n0 + sr) * Dd + d]);
            }
            xs[sc + j][sr] = xv;
            wsm[sc + j][sr] = wv;
        }
        __syncthreads();
        const int dmax = min(64, Dd - d0);
        for (int d = 0; d < dmax; ++d) {
            float4 av = *(const float4*)&xs[d][tb4];
            float4 wv = *(const float4*)&wsm[d][tn4];
            float a[4] = {av.x, av.y, av.z, av.w};
            float wq[4] = {wv.x, wv.y, wv.z, wv.w};
#pragma unroll
            for (int i = 0; i < 4; ++i)
#pragma unroll
                for (int j = 0; j < 4; ++j)
                    c[i][j] = fmaf(a[i], wq[j], c[i][j]);
        }
        __syncthreads();
    }
#pragma unroll
    for (int i = 0; i < 4; ++i)
#pragma unroll
        for (int j = 0; j < 4; ++j) {
            float val = __fadd_rn(c[i][j], bin[m * Nn + n0 + tn4 + j]);
            ext[(size_t)(m * Bb + b0 + tb4 + i) * Nn + n0 + tn4 + j] = val;
        }
}

// ---- grid barrier (r8-verified v3): pure relaxed-atomic flag protocol, monotone,
// poison-tolerant (0xAAAAAAAA < 1 as int -> no zero-init). NO fences anywhere.
// 256 blocks: block 0's first 256 threads poll one flag each.
__device__ __forceinline__ void gbar(int* __restrict__ flags, int* __restrict__ rel,
                                     int t, int wg, int tid) {
    __syncthreads();                      // vmcnt(0): this block's spike atomics acked
    if (tid == 0)
        __hip_atomic_store(&flags[wg * FLAGSTRIDE], t + 1,
                           __ATOMIC_RELAXED, __HIP_MEMORY_SCOPE_AGENT);
    if (wg == 0) {
        if (tid < NBLK) {
            long spin = 0;
            while (__hip_atomic_load(&flags[tid * FLAGSTRIDE],
                                     __ATOMIC_RELAXED, __HIP_MEMORY_SCOPE_AGENT) < t + 1) {
                __builtin_amdgcn_s_sleep(2);
                if (++spin > SPINMAX) break;   // bail: wrong answer beats a hang
            }
        }
        __syncthreads();
        if (tid == 0)
            __hip_atomic_store(rel, t + 1, __ATOMIC_RELAXED, __HIP_MEMORY_SCOPE_AGENT);
    } else if (tid == 0) {
        long spin = 0;
        while (__hip_atomic_load(rel, __ATOMIC_RELAXED, __HIP_MEMORY_SCOPE_AGENT) < t + 1) {
            __builtin_amdgcn_s_sleep(8);
            if (++spin > SPINMAX) break;
        }
    }
    __syncthreads();
}

// ---------------- persistent 16-tick LIF: 256 blocks x 512 thr, tile 64b x 128n -----
// Halves the redundant spike-A L3-atomic traffic vs the 512-block 64x64 tiling
// (each (m,bt) A-tile now loaded by 4 nt-blocks instead of 8). Per-wave fragment
// code identical to the r8/r11-verified kernel (8 waves -> 32x32 wave tiles).
// LDS 48 KB, 1 block/CU x 8 waves (same waves/CU as before).
__global__ void __launch_bounds__(512, 2)
k_ticks(const signed char* __restrict__ Wc,
        signed char* __restrict__ Sp0,
        signed char* __restrict__ Sp1,
        const float* __restrict__ ext,
        float* __restrict__ out,
        int* __restrict__ flags,
        int* __restrict__ rel) {
    __shared__ __align__(16) signed char sA[2][64][128];    // 16 KB
    __shared__ __align__(16) signed char sB[2][128][128];   // 32 KB

    const int wg = blockIdx.x;           // 256: m(8) x bt(8) x nt(4)
    const int m  = wg & 7;               // mesh -> XCD affinity heuristic
    const int bt = (wg >> 3) & 7;
    const int nt = wg >> 6;              // 0..3
    const int b0 = bt * 64;
    const int n0 = nt * 128;
    const int pm = (m + 7) & 7;

    const int tid  = threadIdx.x;        // 0..511
    const int w    = tid >> 6;           // 0..7
    const int lane = tid & 63;
    const int bh   = w & 1;              // 32-row half of b-tile
    const int nh   = w >> 1;             // 0..3: 32-col slice of n-tile
    const int quad = lane >> 4;
    const int li   = lane & 15;
    const int lx   = li & 7;             // read-side swizzle key

    // staging coords: A 1 chunk/thread (64 rows x 8), B 2 chunks/thread (128 rows x 8)
    const int rowA  = tid >> 3;
    const int cnkA  = tid & 7;
    const int gcolA = cnkA * 16;
    const int scolA = (cnkA ^ (rowA & 7)) * 16;
    int rowB[2], gcolB[2], scolB[2];
#pragma unroll
    for (int j = 0; j < 2; ++j) {
        int ch = tid + j * 512;
        rowB[j]  = ch >> 3;
        int cnk  = ch & 7;
        gcolB[j] = cnk * 16;
        scolB[j] = (cnk ^ (rowB[j] & 7)) * 16;
    }

    float decs[2]; int offs[2]; int nels[2];
#pragma unroll
    for (int tn = 0; tn < 2; ++tn) {
        int n = n0 + nh * 32 + tn * 16 + li;
        nels[tn] = n;
        decs[tn] = (n < NEe) ? 0.5f : DEC_I;
        offs[tn] = (n < NEe) ? n : (n + 103);   // i-region of spike row starts at 512
    }
    const int bbase = b0 + bh * 32;

    const signed char* WcBase = Wc + (size_t)(m * Nn + n0) * WCROW;

    // per-thread persistent state in registers for all 16 ticks
    float extr[2][2][4];
#pragma unroll
    for (int tb = 0; tb < 2; ++tb)
#pragma unroll
        for (int tn = 0; tn < 2; ++tn)
#pragma unroll
            for (int r = 0; r < 4; ++r) {
                int b = bbase + tb * 16 + quad * 4 + r;
                extr[tb][tn][r] = ext[(size_t)(m * Bb + b) * Nn + nels[tn]];
            }
    float vmem[2][2][4];
    int cnt[2][2];
#pragma unroll
    for (int tb = 0; tb < 2; ++tb)
#pragma unroll
        for (int tn = 0; tn < 2; ++tn) {
            cnt[tb][tn] = 0;
#pragma unroll
            for (int r = 0; r < 4; ++r) vmem[tb][tn][r] = 0.0f;
        }

    // tick-0 pad-zeroing (r9/r11-verified): nt==0 blocks zero the pad bytes of their
    // 64 rows in both buffers; ordered before tick-1 reads by gbar(t0)
    if (nt == 0) {
        for (int idx = tid; idx < 64 * 128 * 2; idx += 512) {
            int bufsel = idx >> 13;
            int rr = (idx >> 7) & 63;
            int p  = idx & 127;
            int off = (p < 103) ? (409 + p) : (615 + (p - 103));
            signed char* base = (bufsel ? Sp1 : Sp0) + (size_t)(m * Bb + b0 + rr) * SPROW + off;
            __hip_atomic_store(base, (signed char)0, __ATOMIC_RELAXED, __HIP_MEMORY_SCOPE_AGENT);
        }
    }

    for (int t = 0; t < Tt; ++t) {
        signed char* SR = (t & 1) ? Sp1 : Sp0;
        signed char* SW = (t & 1) ? Sp0 : Sp1;
        signed char* AbasePrev = SR + (size_t)(pm * Bb + b0) * SPROW;
        signed char* AbaseOwn  = SR + (size_t)(m  * Bb + b0) * SPROW;

        float c[2][2][4];

        if (t == 0) {
            // spikes all zero: c = ((ext + 0) + 0) + 0, exact fadd chain as GEMM path
#pragma unroll
            for (int tb = 0; tb < 2; ++tb)
#pragma unroll
                for (int tn = 0; tn < 2; ++tn)
#pragma unroll
                    for (int r = 0; r < 4; ++r)
                        c[tb][tn][r] = __fadd_rn(__fadd_rn(__fadd_rn(extr[tb][tn][r], 0.0f), 0.0f), 0.0f);
        } else {
            v4i acc[2][2];
#pragma unroll
            for (int tb = 0; tb < 2; ++tb)
#pragma unroll
                for (int tn = 0; tn < 2; ++tn) acc[tb][tn] = (v4i){0, 0, 0, 0};

            // stage chunk 0 (k0=0 -> prev-mesh e segment); A via agent atomics (L3)
            {
                long* ap = (long*)(AbasePrev + (size_t)rowA * SPROW + gcolA);
                LV tmp;
                tmp.l[0] = __hip_atomic_load(ap,     __ATOMIC_RELAXED, __HIP_MEMORY_SCOPE_AGENT);
                tmp.l[1] = __hip_atomic_load(ap + 1, __ATOMIC_RELAXED, __HIP_MEMORY_SCOPE_AGENT);
                *(v4i*)&sA[0][rowA][scolA] = tmp.v;
#pragma unroll
                for (int j = 0; j < 2; ++j)
                    *(v4i*)&sB[0][rowB[j]][scolB[j]] =
                        *(const v4i*)(WcBase + (size_t)rowB[j] * WCROW + gcolB[j]);
            }
            __syncthreads();

            for (int it = 0; it < 9; ++it) {
                const int buf = it & 1;
                v4i nA, nB[2];
                if (it < 8) {
                    const int k0 = (it + 1) * 128;
                    signed char* ab; int ko;
                    if (k0 < 512) { ab = AbasePrev; ko = k0; }
                    else          { ab = AbaseOwn;  ko = k0 - 512; }
                    long* ap = (long*)(ab + (size_t)rowA * SPROW + ko + gcolA);
                    LV tmp;
                    tmp.l[0] = __hip_atomic_load(ap,     __ATOMIC_RELAXED, __HIP_MEMORY_SCOPE_AGENT);
                    tmp.l[1] = __hip_atomic_load(ap + 1, __ATOMIC_RELAXED, __HIP_MEMORY_SCOPE_AGENT);
                    nA = tmp.v;
#pragma unroll
                    for (int j = 0; j < 2; ++j)
                        nB[j] = *(const v4i*)(WcBase + (size_t)rowB[j] * WCROW + k0 + gcolB[j]);
                }
                // compute current chunk: 2 k-steps of 64 (swizzled fragment reads)
#pragma unroll
                for (int ks = 0; ks < 128; ks += 64) {
                    const int c0 = (((ks >> 4) + quad) ^ lx) * 16;
                    v4i af0 = *(const v4i*)&sA[buf][bh * 32 + li][c0];
                    v4i af1 = *(const v4i*)&sA[buf][bh * 32 + 16 + li][c0];
#pragma unroll
                    for (int tn = 0; tn < 2; ++tn) {
                        v4i bfr = *(const v4i*)&sB[buf][nh * 32 + tn * 16 + li][c0];
                        acc[0][tn] = __builtin_amdgcn_mfma_i32_16x16x64_i8(af0, bfr, acc[0][tn], 0, 0, 0);
                        acc[1][tn] = __builtin_amdgcn_mfma_i32_16x16x64_i8(af1, bfr, acc[1][tn], 0, 0, 0);
                    }
                }
                if (it < 8) {
                    const int nb = buf ^ 1;
                    *(v4i*)&sA[nb][rowA][scolA] = nA;
#pragma unroll
                    for (int j = 0; j < 2; ++j)
                        *(v4i*)&sB[nb][rowB[j]][scolB[j]] = nB[j];
                }
                __syncthreads();
                // segment flushes preserve the reference's exact fp32 add order:
                // c = ((ext_proj+inter) + Erec) + Irec; each partial an exact integer.
                if (it == 3) {
#pragma unroll
                    for (int tb = 0; tb < 2; ++tb)
#pragma unroll
                        for (int tn = 0; tn < 2; ++tn) {
#pragma unroll
                            for (int r = 0; r < 4; ++r)
                                c[tb][tn][r] = __fadd_rn(extr[tb][tn][r], (float)acc[tb][tn][r]);
                            acc[tb][tn] = (v4i){0, 0, 0, 0};
                        }
                } else if (it == 7 || it == 8) {
#pragma unroll
                    for (int tb = 0; tb < 2; ++tb)
#pragma unroll
                        for (int tn = 0; tn < 2; ++tn) {
#pragma unroll
                            for (int r = 0; r < 4; ++r)
                                c[tb][tn][r] = __fadd_rn(c[tb][tn][r], (float)acc[tb][tn][r]);
                            acc[tb][tn] = (v4i){0, 0, 0, 0};
                        }
                }
            }
        }

        // LIF update, exact np op order: v' = (v*decay) + c; spike iff v' >= 1.0
        // spikes published via agent-scope atomic byte stores (write-through)
#pragma unroll
        for (int tb = 0; tb < 2; ++tb)
#pragma unroll
            for (int tn = 0; tn < 2; ++tn)
#pragma unroll
                for (int r = 0; r < 4; ++r) {
                    float vn = __fadd_rn(__fmul_rn(vmem[tb][tn][r], decs[tn]), c[tb][tn][r]);
                    int s = (vn >= 1.0f) ? 1 : 0;
                    vmem[tb][tn][r] = s ? 0.0f : vn;
                    cnt[tb][tn] += s << (r * 8);
                    if (t < Tt - 1) {
                        int b = bbase + tb * 16 + quad * 4 + r;
                        signed char* sp = SW + (size_t)(m * Bb + b) * SPROW + offs[tn];
                        __hip_atomic_store(sp, (signed char)s,
                                           __ATOMIC_RELAXED, __HIP_MEMORY_SCOPE_AGENT);
                    }
                }
        if (t < Tt - 1) gbar(flags, rel, t, wg, tid);
    }

    // out[b][m*N + n] = spike count (single write at the end)
#pragma unroll
    for (int tb = 0; tb < 2; ++tb)
#pragma unroll
        for (int tn = 0; tn < 2; ++tn)
#pragma unroll
            for (int r = 0; r < 4; ++r) {
                int b = bbase + tb * 16 + quad * 4 + r;
                out[(size_t)b * (Mm * Nn) + m * Nn + nels[tn]] =
                    (float)((cnt[tb][tn] >> (r * 8)) & 0xff);
            }
}

extern "C" void kernel_launch(void* const* d_in, const int* in_sizes, int n_in,
                              void* d_out, int out_size, void* d_ws, size_t ws_size,
                              hipStream_t stream) {
    const float* x    = (const float*)d_in[0];
    const float* Win  = (const float*)d_in[1];
    const float* bin  = (const float*)d_in[2];
    const float* Wint = (const float*)d_in[3];
    const float* WEE  = (const float*)d_in[4];
    const float* WEI  = (const float*)d_in[5];
    const float* WIE  = (const float*)d_in[6];
    const float* WII  = (const float*)d_in[7];
    float* out = (float*)d_out;

    char* ws = (char*)d_ws;
    signed char* Wc  = (signed char*)ws;                       // 8*512*1152 = 4,718,592
    signed char* Sp0 = (signed char*)(ws + 4718592);           // 8*512*640  = 2,621,440
    signed char* Sp1 = Sp0 + 2621440;
    int* flags = (int*)(ws + 4718592 + 2 * 2621440);           // 256*64 B (poison-tolerant)
    int* rel   = (int*)(ws + 4718592 + 2 * 2621440 + 32768);   // 64 B (poison-tolerant)
    float* extw = (float*)(ws + 4718592 + 2 * 2621440 + 32768 + 64);  // 8,388,608

    k_pack<<<(Mm * Nn * WCROW / 4 + 255) / 256, 256, 0, stream>>>(Wint, WEE, WEI, WIE, WII, Wc);
    k_ext<<<512, 256, 0, stream>>>(x, Win, bin, extw);
    k_ticks<<<NBLK, 512, 0, stream>>>(Wc, Sp0, Sp1, (const float*)extw, out, flags, rel);
}

// Round 13
// 243.311 us; speedup vs baseline: 1.0436x; 1.0436x over previous
//
#include <hip/hip_runtime.h>
#include <hip/hip_bf16.h>

#define Mm 8
#define Nn 512
#define NEe 409
#define NIi 103
#define Bb 512
#define Dd 243
#define Tt 16
#define SPROW 640      // spike row bytes (i8): e[0:409) pad[409:512) i[512:615) pad[615:640)
#define WCROW 1152     // packed weight row bytes (i8): inter(512) | E-rec(512) | I-rec(128)
#define DEC_I 0.33333334f  // (float)(1.0 - 1.0/1.5)
#define NBLK 256
#define FLAGSTRIDE 16  // one flag per 64B cache line
#define SPINMAX 1000000L

typedef int v4i __attribute__((ext_vector_type(4)));
union LV { long l[2]; v4i v; };

__device__ __forceinline__ float quantf(float w) {
    // fake_quant forward == clip(round-half-even(w), -8, 7)  (step = 1.0)
    float q = rintf(w);
    return fminf(fmaxf(q, -8.0f), 7.0f);
}

// ---------------- pack quantized recurrent weights as i8, 4 k's per thread ----------
__global__ void k_pack(const float* __restrict__ Wint, const float* __restrict__ WEE,
                       const float* __restrict__ WEI, const float* __restrict__ WIE,
                       const float* __restrict__ WII, signed char* __restrict__ Wc) {
    int q = blockIdx.x * 256 + threadIdx.x;          // quad index
    if (q >= (Mm * Nn * WCROW) / 4) return;
    int k0 = (q * 4) % WCROW;
    int n  = ((q * 4) / WCROW) & (Nn - 1);
    int m  = (q * 4) / (WCROW * Nn);
    char out4[4];
#pragma unroll
    for (int j = 0; j < 4; ++j) {
        int k = k0 + j;
        float w = 0.0f;
        if (k < 512) {
            if (k < NEe) w = Wint[((((m + 7) & 7) * Nn) + n) * NEe + k];
        } else if (k < 1024) {
            int jj = k - 512;
            if (jj < NEe) w = (n < NEe) ? WEE[((m * NEe) + n) * NEe + jj]
                                        : WEI[((m * NIi) + (n - NEe)) * NEe + jj];
        } else {
            int jj = k - 1024;
            if (jj < NIi) w = (n < NEe) ? WIE[((m * NEe) + n) * NIi + jj]
                                        : WII[((m * NIi) + (n - NEe)) * NIi + jj];
        }
        out4[j] = (signed char)(int)quantf(w);
    }
    *(int*)&Wc[q * 4] = *(int*)out4;
}

// ---------------- ext_proj = x @ qW_in^T + b_in  (fp32, sequential over d; r8 exact) -
__global__ void k_ext(const float* __restrict__ x, const float* __restrict__ Win,
                      const float* __restrict__ bin, float* __restrict__ ext) {
    __shared__ float xs[64][68];
    __shared__ float wsm[64][68];
    const int bid = blockIdx.x;          // 512 blocks: m(8) x bt(8) x nt(8)
    const int m  = bid >> 6;
    const int bt = (bid >> 3) & 7;
    const int nt = bid & 7;
    const int b0 = bt * 64, n0 = nt * 64;
    const int t = threadIdx.x;
    const int tb4 = (t & 15) * 4;
    const int tn4 = (t >> 4) * 4;
    const int sr = t >> 2;
    const int sc = (t & 3) * 16;
    float c[4][4];
#pragma unroll
    for (int i = 0; i < 4; ++i)
#pragma unroll
        for (int j = 0; j < 4; ++j) c[i][j] = 0.0f;

    for (int d0 = 0; d0 < Dd; d0 += 64) {
#pragma unroll
        for (int j = 0; j < 16; ++j) {
            int d = d0 + sc + j;
            float xv = 0.0f, wv = 0.0f;
            if (d < Dd) {
                xv = x[(b0 + sr) * Dd + d];
                wv = quantf(Win[((m * Nn) + n0 + sr) * Dd + d]);
            }
            xs[sc + j][sr] = xv;
            wsm[sc + j][sr] = wv;
        }
        __syncthreads();
        const int dmax = min(64, Dd - d0);
        for (int d = 0; d < dmax; ++d) {
            float4 av = *(const float4*)&xs[d][tb4];
            float4 wv = *(const float4*)&wsm[d][tn4];
            float a[4] = {av.x, av.y, av.z, av.w};
            float wq[4] = {wv.x, wv.y, wv.z, wv.w};
#pragma unroll
            for (int i = 0; i < 4; ++i)
#pragma unroll
                for (int j = 0; j < 4; ++j)
                    c[i][j] = fmaf(a[i], wq[j], c[i][j]);
        }
        __syncthreads();
    }
#pragma unroll
    for (int i = 0; i < 4; ++i)
#pragma unroll
        for (int j = 0; j < 4; ++j) {
            float val = __fadd_rn(c[i][j], bin[m * Nn + n0 + tn4 + j]);
            ext[(size_t)(m * Bb + b0 + tb4 + i) * Nn + n0 + tn4 + j] = val;
        }
}

// ---------------- persistent 16-tick LIF: neighborhood dataflow sync ----------------
// 256 blocks x 512 thr, tile 64b x 128n (r12-verified GEMM). Instead of a global
// barrier per tick, each block waits only on the 12 flags of mesh-groups
// {m-1, m, m+1} x nt(4) at its bt: m-1 = producer of inter rows (RAW), m = own-rec
// rows (RAW), m+1 = reader of this block's rows at tick t-1 (WAR on ping-pong).
// Flags monotone + poison-tolerant; publish mechanism identical to the r8-verified
// barrier (spike agent-atomics -> __syncthreads vmcnt drain -> relaxed flag store).
__global__ void __launch_bounds__(512, 2)
k_ticks(const signed char* __restrict__ Wc,
        signed char* __restrict__ Sp0,
        signed char* __restrict__ Sp1,
        const float* __restrict__ ext,
        float* __restrict__ out,
        int* __restrict__ flags) {
    __shared__ __align__(16) signed char sA[2][64][128];    // 16 KB
    __shared__ __align__(16) signed char sB[2][128][128];   // 32 KB

    const int wg = blockIdx.x;           // 256: m(8) x bt(8) x nt(4)
    const int m  = wg & 7;               // mesh -> XCD affinity heuristic
    const int bt = (wg >> 3) & 7;
    const int nt = wg >> 6;              // 0..3
    const int b0 = bt * 64;
    const int n0 = nt * 128;
    const int pm = (m + 7) & 7;
    const int nm = (m + 1) & 7;

    const int tid  = threadIdx.x;        // 0..511
    const int w    = tid >> 6;           // 0..7
    const int lane = tid & 63;
    const int bh   = w & 1;              // 32-row half of b-tile
    const int nh   = w >> 1;             // 0..3: 32-col slice of n-tile
    const int quad = lane >> 4;
    const int li   = lane & 15;
    const int lx   = li & 7;             // read-side swizzle key

    // wait-set flag index for tid<12: mesh {pm,m,nm}[tid>>2], nt'=tid&3, same bt
    int waitIdx = 0;
    if (tid < 12) {
        int g  = tid >> 2;
        int mm = (g == 0) ? pm : ((g == 1) ? m : nm);
        waitIdx = (((tid & 3) << 6) | (bt << 3) | mm) * FLAGSTRIDE;
    }

    // staging coords: A 1 chunk/thread (64 rows x 8), B 2 chunks/thread (128 rows x 8)
    const int rowA  = tid >> 3;
    const int cnkA  = tid & 7;
    const int gcolA = cnkA * 16;
    const int scolA = (cnkA ^ (rowA & 7)) * 16;
    int rowB[2], gcolB[2], scolB[2];
#pragma unroll
    for (int j = 0; j < 2; ++j) {
        int ch = tid + j * 512;
        rowB[j]  = ch >> 3;
        int cnk  = ch & 7;
        gcolB[j] = cnk * 16;
        scolB[j] = (cnk ^ (rowB[j] & 7)) * 16;
    }

    float decs[2]; int offs[2]; int nels[2];
#pragma unroll
    for (int tn = 0; tn < 2; ++tn) {
        int n = n0 + nh * 32 + tn * 16 + li;
        nels[tn] = n;
        decs[tn] = (n < NEe) ? 0.5f : DEC_I;
        offs[tn] = (n < NEe) ? n : (n + 103);   // i-region of spike row starts at 512
    }
    const int bbase = b0 + bh * 32;

    const signed char* WcBase = Wc + (size_t)(m * Nn + n0) * WCROW;

    // per-thread persistent state in registers for all 16 ticks
    float extr[2][2][4];
#pragma unroll
    for (int tb = 0; tb < 2; ++tb)
#pragma unroll
        for (int tn = 0; tn < 2; ++tn)
#pragma unroll
            for (int r = 0; r < 4; ++r) {
                int b = bbase + tb * 16 + quad * 4 + r;
                extr[tb][tn][r] = ext[(size_t)(m * Bb + b) * Nn + nels[tn]];
            }
    float vmem[2][2][4];
    int cnt[2][2];
#pragma unroll
    for (int tb = 0; tb < 2; ++tb)
#pragma unroll
        for (int tn = 0; tn < 2; ++tn) {
            cnt[tb][tn] = 0;
#pragma unroll
            for (int r = 0; r < 4; ++r) vmem[tb][tn][r] = 0.0f;
        }

    // tick-0 pad-zeroing (r9/r11-verified): nt==0 blocks zero the pad bytes of their
    // 64 rows in both buffers; visible to consumers via this block's flag(1) post
    if (nt == 0) {
        for (int idx = tid; idx < 64 * 128 * 2; idx += 512) {
            int bufsel = idx >> 13;
            int rr = (idx >> 7) & 63;
            int p  = idx & 127;
            int off = (p < 103) ? (409 + p) : (615 + (p - 103));
            signed char* base = (bufsel ? Sp1 : Sp0) + (size_t)(m * Bb + b0 + rr) * SPROW + off;
            __hip_atomic_store(base, (signed char)0, __ATOMIC_RELAXED, __HIP_MEMORY_SCOPE_AGENT);
        }
    }

    for (int t = 0; t < Tt; ++t) {
        signed char* SR = (t & 1) ? Sp1 : Sp0;
        signed char* SW = (t & 1) ? Sp0 : Sp1;
        signed char* AbasePrev = SR + (size_t)(pm * Bb + b0) * SPROW;
        signed char* AbaseOwn  = SR + (size_t)(m  * Bb + b0) * SPROW;

        // neighborhood wait: 12 flags {pm,m,nm} x nt' at level t (t>=1).
        // pm/m: RAW (their tick t-1 spike writes); nm: WAR (finished reading the
        // buffer this block overwrites at end of tick t).
        if (t > 0) {
            if (tid < 12) {
                long spin = 0;
                while (__hip_atomic_load(&flags[waitIdx],
                                         __ATOMIC_RELAXED, __HIP_MEMORY_SCOPE_AGENT) < t) {
                    __builtin_amdgcn_s_sleep(2);
                    if (++spin > SPINMAX) break;   // bail: wrong answer beats a hang
                }
            }
            __syncthreads();
        }

        float c[2][2][4];

        if (t == 0) {
            // spikes all zero: c = ((ext + 0) + 0) + 0, exact fadd chain as GEMM path
#pragma unroll
            for (int tb = 0; tb < 2; ++tb)
#pragma unroll
                for (int tn = 0; tn < 2; ++tn)
#pragma unroll
                    for (int r = 0; r < 4; ++r)
                        c[tb][tn][r] = __fadd_rn(__fadd_rn(__fadd_rn(extr[tb][tn][r], 0.0f), 0.0f), 0.0f);
        } else {
            v4i acc[2][2];
#pragma unroll
            for (int tb = 0; tb < 2; ++tb)
#pragma unroll
                for (int tn = 0; tn < 2; ++tn) acc[tb][tn] = (v4i){0, 0, 0, 0};

            // stage chunk 0 (k0=0 -> prev-mesh e segment); A via agent atomics (L3)
            {
                long* ap = (long*)(AbasePrev + (size_t)rowA * SPROW + gcolA);
                LV tmp;
                tmp.l[0] = __hip_atomic_load(ap,     __ATOMIC_RELAXED, __HIP_MEMORY_SCOPE_AGENT);
                tmp.l[1] = __hip_atomic_load(ap + 1, __ATOMIC_RELAXED, __HIP_MEMORY_SCOPE_AGENT);
                *(v4i*)&sA[0][rowA][scolA] = tmp.v;
#pragma unroll
                for (int j = 0; j < 2; ++j)
                    *(v4i*)&sB[0][rowB[j]][scolB[j]] =
                        *(const v4i*)(WcBase + (size_t)rowB[j] * WCROW + gcolB[j]);
            }
            __syncthreads();

            for (int it = 0; it < 9; ++it) {
                const int buf = it & 1;
                v4i nA, nB[2];
                if (it < 8) {
                    const int k0 = (it + 1) * 128;
                    signed char* ab; int ko;
                    if (k0 < 512) { ab = AbasePrev; ko = k0; }
                    else          { ab = AbaseOwn;  ko = k0 - 512; }
                    long* ap = (long*)(ab + (size_t)rowA * SPROW + ko + gcolA);
                    LV tmp;
                    tmp.l[0] = __hip_atomic_load(ap,     __ATOMIC_RELAXED, __HIP_MEMORY_SCOPE_AGENT);
                    tmp.l[1] = __hip_atomic_load(ap + 1, __ATOMIC_RELAXED, __HIP_MEMORY_SCOPE_AGENT);
                    nA = tmp.v;
#pragma unroll
                    for (int j = 0; j < 2; ++j)
                        nB[j] = *(const v4i*)(WcBase + (size_t)rowB[j] * WCROW + k0 + gcolB[j]);
                }
                // compute current chunk: 2 k-steps of 64 (swizzled fragment reads)
#pragma unroll
                for (int ks = 0; ks < 128; ks += 64) {
                    const int c0 = (((ks >> 4) + quad) ^ lx) * 16;
                    v4i af0 = *(const v4i*)&sA[buf][bh * 32 + li][c0];
                    v4i af1 = *(const v4i*)&sA[buf][bh * 32 + 16 + li][c0];
#pragma unroll
                    for (int tn = 0; tn < 2; ++tn) {
                        v4i bfr = *(const v4i*)&sB[buf][nh * 32 + tn * 16 + li][c0];
                        acc[0][tn] = __builtin_amdgcn_mfma_i32_16x16x64_i8(af0, bfr, acc[0][tn], 0, 0, 0);
                        acc[1][tn] = __builtin_amdgcn_mfma_i32_16x16x64_i8(af1, bfr, acc[1][tn], 0, 0, 0);
                    }
                }
                if (it < 8) {
                    const int nb = buf ^ 1;
                    *(v4i*)&sA[nb][rowA][scolA] = nA;
#pragma unroll
                    for (int j = 0; j < 2; ++j)
                        *(v4i*)&sB[nb][rowB[j]][scolB[j]] = nB[j];
                }
                __syncthreads();
                // segment flushes preserve the reference's exact fp32 add order:
                // c = ((ext_proj+inter) + Erec) + Irec; each partial an exact integer.
                if (it == 3) {
#pragma unroll
                    for (int tb = 0; tb < 2; ++tb)
#pragma unroll
                        for (int tn = 0; tn < 2; ++tn) {
#pragma unroll
                            for (int r = 0; r < 4; ++r)
                                c[tb][tn][r] = __fadd_rn(extr[tb][tn][r], (float)acc[tb][tn][r]);
                            acc[tb][tn] = (v4i){0, 0, 0, 0};
                        }
                } else if (it == 7 || it == 8) {
#pragma unroll
                    for (int tb = 0; tb < 2; ++tb)
#pragma unroll
                        for (int tn = 0; tn < 2; ++tn) {
#pragma unroll
                            for (int r = 0; r < 4; ++r)
                                c[tb][tn][r] = __fadd_rn(c[tb][tn][r], (float)acc[tb][tn][r]);
                            acc[tb][tn] = (v4i){0, 0, 0, 0};
                        }
                }
            }
        }

        // LIF update, exact np op order: v' = (v*decay) + c; spike iff v' >= 1.0
        // spikes published via agent-scope atomic byte stores (write-through)
#pragma unroll
        for (int tb = 0; tb < 2; ++tb)
#pragma unroll
            for (int tn = 0; tn < 2; ++tn)
#pragma unroll
                for (int r = 0; r < 4; ++r) {
                    float vn = __fadd_rn(__fmul_rn(vmem[tb][tn][r], decs[tn]), c[tb][tn][r]);
                    int s = (vn >= 1.0f) ? 1 : 0;
                    vmem[tb][tn][r] = s ? 0.0f : vn;
                    cnt[tb][tn] += s << (r * 8);
                    if (t < Tt - 1) {
                        int b = bbase + tb * 16 + quad * 4 + r;
                        signed char* sp = SW + (size_t)(m * Bb + b) * SPROW + offs[tn];
                        __hip_atomic_store(sp, (signed char)s,
                                           __ATOMIC_RELAXED, __HIP_MEMORY_SCOPE_AGENT);
                    }
                }
        // post completion flag for tick t (covers this tick's reads AND writes)
        if (t < Tt - 1) {
            __syncthreads();              // vmcnt(0): spike atomics + LDS use complete
            if (tid == 0)
                __hip_atomic_store(&flags[wg * FLAGSTRIDE], t + 1,
                                   __ATOMIC_RELAXED, __HIP_MEMORY_SCOPE_AGENT);
        }
    }

    // out[b][m*N + n] = spike count (single write at the end)
#pragma unroll
    for (int tb = 0; tb < 2; ++tb)
#pragma unroll
        for (int tn = 0; tn < 2; ++tn)
#pragma unroll
            for (int r = 0; r < 4; ++r) {
                int b = bbase + tb * 16 + quad * 4 + r;
                out[(size_t)b * (Mm * Nn) + m * Nn + nels[tn]] =
                    (float)((cnt[tb][tn] >> (r * 8)) & 0xff);
            }
}

extern "C" void kernel_launch(void* const* d_in, const int* in_sizes, int n_in,
                              void* d_out, int out_size, void* d_ws, size_t ws_size,
                              hipStream_t stream) {
    const float* x    = (const float*)d_in[0];
    const float* Win  = (const float*)d_in[1];
    const float* bin  = (const float*)d_in[2];
    const float* Wint = (const float*)d_in[3];
    const float* WEE  = (const float*)d_in[4];
    const float* WEI  = (const float*)d_in[5];
    const float* WIE  = (const float*)d_in[6];
    const float* WII  = (const float*)d_in[7];
    float* out = (float*)d_out;

    char* ws = (char*)d_ws;
    signed char* Wc  = (signed char*)ws;                       // 8*512*1152 = 4,718,592
    signed char* Sp0 = (signed char*)(ws + 4718592);           // 8*512*640  = 2,621,440
    signed char* Sp1 = Sp0 + 2621440;
    int* flags = (int*)(ws + 4718592 + 2 * 2621440);           // 256*64 B (poison-tolerant)
    float* extw = (float*)(ws + 4718592 + 2 * 2621440 + 32768);  // 8,388,608

    k_pack<<<(Mm * Nn * WCROW / 4 + 255) / 256, 256, 0, stream>>>(Wint, WEE, WEI, WIE, WII, Wc);
    k_ext<<<512, 256, 0, stream>>>(x, Win, bin, extw);
    k_ticks<<<NBLK, 512, 0, stream>>>(Wc, Sp0, Sp1, (const float*)extw, out, flags);
}